// Round 1
// baseline (91.819 us; speedup 1.0000x reference)
//
#include <hip/hip_runtime.h>

// GatedRelevanceNetwork: B=8, L1=L2=64, d=256, K=32
// out[b,m,n] = sum_k u[k] * ( g*btp + (1-g)*tanh(a1d[m,k]+a2d[n,k]) + b[k] )
//   btp[b,m,n,k] = a1[b,m,:] * Wb[k] * a2[b,n,:]^T
//   g = sigmoid(a1g[m,k]+a2g[n,k]+bg[k])
// Block (b,k): R = Wb[k] @ a2^T (256x64), btp = a1 @ R (64x64), epilogue, per-k
// contribution to ws; reduce kernel sums over k.

#define LSTR 264   // padded stride (elems) for 256-wide f16 rows: bank step 4 -> free 2-way
#define WSTR 40    // padded stride for 32-wide Wb chunk rows

typedef _Float16 half8 __attribute__((ext_vector_type(8)));
typedef _Float16 half4x __attribute__((ext_vector_type(4)));
typedef float floatx4 __attribute__((ext_vector_type(4)));

__global__ __launch_bounds__(512, 2) void grn_main_335007449190(
    const float* __restrict__ arg1, const float* __restrict__ arg2,
    const float* __restrict__ Wb,   const float* __restrict__ Wd,
    const float* __restrict__ Wg,   const float* __restrict__ bg,
    const float* __restrict__ bvec, const float* __restrict__ u,
    float* __restrict__ contrib,    float* __restrict__ outp, int use_atomic)
{
    __shared__ _Float16 sA1[64 * LSTR];   // a1[m][e]
    __shared__ _Float16 sA2[64 * LSTR];   // a2[n][f]
    __shared__ _Float16 sRT[64 * LSTR];   // R^T[n][e]
    __shared__ _Float16 sWb[256 * WSTR];  // Wb chunk [e][f_local]
    __shared__ float    sWcol[1024];      // Wd1|Wd2|Wg1|Wg2 columns k
    __shared__ float    sDots[256];       // a1d|a2d|a1g|a2g  (64 each)

    const int t   = threadIdx.x;
    const int bi  = blockIdx.x >> 5;
    const int k   = blockIdx.x & 31;
    const int w   = t >> 6;        // wave 0..7
    const int ln  = t & 63;
    const int q   = ln >> 4;       // quad 0..3
    const int l16 = ln & 15;

    // ---- stage a1, a2 (f32 -> f16), and Wd/Wg columns ----
    const float4* A1g = reinterpret_cast<const float4*>(arg1 + (size_t)bi * 64 * 256);
    const float4* A2g = reinterpret_cast<const float4*>(arg2 + (size_t)bi * 64 * 256);
#pragma unroll
    for (int i = 0; i < 8; ++i) {
        int idx4 = t + i * 512;               // 4096 float4s each
        int m = idx4 >> 6, f = (idx4 & 63) << 2;
        float4 v = A1g[idx4];
        half4x h1 = { (_Float16)v.x, (_Float16)v.y, (_Float16)v.z, (_Float16)v.w };
        *reinterpret_cast<half4x*>(&sA1[m * LSTR + f]) = h1;
        float4 u2 = A2g[idx4];
        half4x h2 = { (_Float16)u2.x, (_Float16)u2.y, (_Float16)u2.z, (_Float16)u2.w };
        *reinterpret_cast<half4x*>(&sA2[m * LSTR + f]) = h2;
    }
    sWcol[t]       = Wd[t * 32 + k];   // t<256: Wd1 col, t>=256: Wd2 col
    sWcol[512 + t] = Wg[t * 32 + k];
    __syncthreads();

    // ---- small dots: a1d/a2d/a1g/a2g (waves 0..3, lane = row index) ----
    if (w < 4) {
        const _Float16* row = (w & 1) ? &sA2[ln * LSTR] : &sA1[ln * LSTR];
        const float* wc = &sWcol[w * 256];
        float s = 0.f;
#pragma unroll 4
        for (int e = 0; e < 256; e += 4) {
            half4x h = *reinterpret_cast<const half4x*>(&row[e]);
            s += (float)h[0] * wc[e]     + (float)h[1] * wc[e + 1]
               + (float)h[2] * wc[e + 2] + (float)h[3] * wc[e + 3];
        }
        sDots[w * 64 + ln] = s;
    }

    // ---- GEMM1: R[e,n] = sum_f Wb[k,e,f]*a2[n,f];  8 chunks of 32 f-cols ----
    floatx4 acc[2][4] = {};   // wave w owns e-rows [w*32, w*32+32), all 64 n
    const float4* Wb4 = reinterpret_cast<const float4*>(Wb) + (size_t)k * 16384;
    for (int c = 0; c < 8; ++c) {
#pragma unroll
        for (int i = 0; i < 4; ++i) {
            int idx4 = t + i * 512;           // 2048 float4s per chunk
            int e = idx4 >> 3, fq = idx4 & 7;
            float4 v = Wb4[(size_t)e * 64 + c * 8 + fq];
            half4x h = { (_Float16)v.x, (_Float16)v.y, (_Float16)v.z, (_Float16)v.w };
            *reinterpret_cast<half4x*>(&sWb[e * WSTR + (fq << 2)]) = h;
        }
        __syncthreads();
        half8 bf[4];
#pragma unroll
        for (int j = 0; j < 4; ++j)
            bf[j] = *reinterpret_cast<const half8*>(&sA2[(j * 16 + l16) * LSTR + c * 32 + q * 8]);
#pragma unroll
        for (int i2 = 0; i2 < 2; ++i2) {
            half8 af = *reinterpret_cast<const half8*>(&sWb[((w * 2 + i2) * 16 + l16) * WSTR + q * 8]);
#pragma unroll
            for (int j = 0; j < 4; ++j)
                acc[i2][j] = __builtin_amdgcn_mfma_f32_16x16x32_f16(af, bf[j], acc[i2][j], 0, 0, 0);
        }
        __syncthreads();
    }

    // ---- write R^T to LDS (f16): C/D layout col=l16, row=q*4+r -> 4 consec e ----
#pragma unroll
    for (int i2 = 0; i2 < 2; ++i2)
#pragma unroll
        for (int j = 0; j < 4; ++j) {
            int e0 = w * 32 + i2 * 16 + q * 4;
            int n  = j * 16 + l16;
            floatx4 a = acc[i2][j];
            half4x h = { (_Float16)a[0], (_Float16)a[1], (_Float16)a[2], (_Float16)a[3] };
            *reinterpret_cast<half4x*>(&sRT[n * LSTR + e0]) = h;
        }
    __syncthreads();

    // ---- GEMM2: btp[m,n] = sum_e a1[m,e] * R[e,n]; wave -> (mt, 2 n-tiles) ----
    floatx4 acc2[2] = {};
    const int mt = w >> 1, np = w & 1;
#pragma unroll
    for (int es = 0; es < 8; ++es) {
        half8 a = *reinterpret_cast<const half8*>(&sA1[(mt * 16 + l16) * LSTR + es * 32 + q * 8]);
#pragma unroll
        for (int tt = 0; tt < 2; ++tt) {
            int nt = np * 2 + tt;
            half8 bb = *reinterpret_cast<const half8*>(&sRT[(nt * 16 + l16) * LSTR + es * 32 + q * 8]);
            acc2[tt] = __builtin_amdgcn_mfma_f32_16x16x32_f16(a, bb, acc2[tt], 0, 0, 0);
        }
    }

    // ---- epilogue: gate, tanh, scale by u[k]; write per-k contribution ----
    const float bgk = bg[k], bk = bvec[k], uk = u[k];
    float* cptr = contrib + ((size_t)(bi * 32 + k)) * 4096;
#pragma unroll
    for (int tt = 0; tt < 2; ++tt) {
        int n = (np * 2 + tt) * 16 + l16;
#pragma unroll
        for (int r = 0; r < 4; ++r) {
            int m = mt * 16 + q * 4 + r;
            float btp = acc2[tt][r];
            float zd  = sDots[m] + sDots[64 + n];
            float sln = 1.f - 2.f / (1.f + __expf(2.f * zd));      // tanh, overflow-safe
            float zg  = sDots[128 + m] + sDots[192 + n] + bgk;
            float g   = 1.f / (1.f + __expf(-zg));                 // sigmoid, overflow-safe
            float val = uk * (g * btp + (1.f - g) * sln + bk);
            if (use_atomic) atomicAdd(&outp[(size_t)bi * 4096 + m * 64 + n], val);
            else            cptr[m * 64 + n] = val;
        }
    }
}

__global__ __launch_bounds__(256) void grn_reduce_335007449190(
    const float* __restrict__ contrib, float* __restrict__ out)
{
    int i  = blockIdx.x * 256 + threadIdx.x;   // 32768 outputs
    int b  = i >> 12;
    int mn = i & 4095;
    const float* p = contrib + (size_t)b * 131072 + mn;
    float s = 0.f;
#pragma unroll
    for (int kk = 0; kk < 32; ++kk) s += p[kk * 4096];
    out[i] = s;
}

extern "C" void kernel_launch(void* const* d_in, const int* in_sizes, int n_in,
                              void* d_out, int out_size, void* d_ws, size_t ws_size,
                              hipStream_t stream) {
    const float* arg1 = (const float*)d_in[0];
    const float* arg2 = (const float*)d_in[1];
    const float* Wb   = (const float*)d_in[2];
    const float* Wd   = (const float*)d_in[3];
    const float* Wg   = (const float*)d_in[4];
    const float* bg   = (const float*)d_in[5];
    const float* bv   = (const float*)d_in[6];
    const float* u    = (const float*)d_in[7];
    float* out = (float*)d_out;

    const size_t need = (size_t)8 * 32 * 4096 * sizeof(float);   // 4 MB
    if (ws_size >= need) {
        float* contrib = (float*)d_ws;
        grn_main_335007449190<<<256, 512, 0, stream>>>(arg1, arg2, Wb, Wd, Wg, bg, bv, u,
                                                       contrib, out, 0);
        grn_reduce_335007449190<<<128, 256, 0, stream>>>(contrib, out);
    } else {
        hipMemsetAsync(d_out, 0, (size_t)out_size * sizeof(float), stream);
        grn_main_335007449190<<<256, 512, 0, stream>>>(arg1, arg2, Wb, Wd, Wg, bg, bv, u,
                                                       nullptr, out, 1);
    }
}

// Round 3
// 91.319 us; speedup vs baseline: 1.0055x; 1.0055x over previous
//
#include <hip/hip_runtime.h>

// GatedRelevanceNetwork: B=8, L1=L2=64, d=256, K=32
// out[b,m,n] = sum_k u[k] * ( g*btp + (1-g)*tanh(a1d[m,k]+a2d[n,k]) + b[k] )
// Block (b,k): R = Wb[k] @ a2^T (256x64), btp = a1 @ R (64x64), epilogue writes
// per-k contribution to ws; reduce kernel sums over k.
// R2: R1's double-buffered Wb pipeline, but sWb[2] aliased with sRT (they are
// never simultaneously live) -> LDS 111 KiB (R1's 144 KiB aborted at launch;
// 124 KiB was the proven R0 max).

#define LSTR 264   // padded stride (elems) for 256-wide f16 rows: bank step 4 -> free 2-way
#define WSTR 40    // padded stride for 32-wide Wb chunk rows

typedef _Float16 half8 __attribute__((ext_vector_type(8)));
typedef _Float16 half4x __attribute__((ext_vector_type(4)));
typedef float floatx4 __attribute__((ext_vector_type(4)));

__global__ __launch_bounds__(512, 2) void grn_main_335007449190(
    const float* __restrict__ arg1, const float* __restrict__ arg2,
    const float* __restrict__ Wb,   const float* __restrict__ Wd,
    const float* __restrict__ Wg,   const float* __restrict__ bg,
    const float* __restrict__ bvec, const float* __restrict__ u,
    float* __restrict__ contrib)
{
    // Layout (bytes):
    //   [0,      33792)  sA1  : a1[m][e] f16, stride LSTR
    //   [33792,  67584)  sA2  : a2[n][f] f16, stride LSTR
    //   [67584, 108544)  union: sWb[2] (2 x 20480, GEMM1 phase)
    //                           sRT (33792, GEMM2 phase) -- never both live
    //   [108544,112640)  sWcol: Wd1|Wd2|Wg1|Wg2 columns k (f32 x 1024)
    //   [112640,113664)  sDots: a1d|a2d|a1g|a2g (f32 x 256)
    __shared__ __align__(16) char smem[113664];
    _Float16* sA1  = reinterpret_cast<_Float16*>(smem);
    _Float16* sA2  = reinterpret_cast<_Float16*>(smem + 33792);
    _Float16* sWb0 = reinterpret_cast<_Float16*>(smem + 67584);
    _Float16* sWb1 = reinterpret_cast<_Float16*>(smem + 67584 + 20480);
    _Float16* sRT  = reinterpret_cast<_Float16*>(smem + 67584);
    float*    sWcol= reinterpret_cast<float*>(smem + 108544);
    float*    sDots= reinterpret_cast<float*>(smem + 112640);
    _Float16* sWbBuf[2] = { sWb0, sWb1 };

    const int t   = threadIdx.x;
    const int bi  = blockIdx.x >> 5;
    const int k   = blockIdx.x & 31;
    const int w   = t >> 6;        // wave 0..7
    const int ln  = t & 63;
    const int q   = ln >> 4;       // quad 0..3
    const int l16 = ln & 15;

    const float4* Wb4 = reinterpret_cast<const float4*>(Wb) + (size_t)k * 16384;

    // ---- stage a1, a2 (f32 -> f16), Wb chunk 0, and Wd/Wg columns ----
    const float4* A1g = reinterpret_cast<const float4*>(arg1 + (size_t)bi * 64 * 256);
    const float4* A2g = reinterpret_cast<const float4*>(arg2 + (size_t)bi * 64 * 256);
#pragma unroll
    for (int i = 0; i < 8; ++i) {
        int idx4 = t + i * 512;               // 4096 float4s each
        int m = idx4 >> 6, f = (idx4 & 63) << 2;
        float4 v = A1g[idx4];
        half4x h1 = { (_Float16)v.x, (_Float16)v.y, (_Float16)v.z, (_Float16)v.w };
        *reinterpret_cast<half4x*>(&sA1[m * LSTR + f]) = h1;
        float4 u2 = A2g[idx4];
        half4x h2 = { (_Float16)u2.x, (_Float16)u2.y, (_Float16)u2.z, (_Float16)u2.w };
        *reinterpret_cast<half4x*>(&sA2[m * LSTR + f]) = h2;
    }
#pragma unroll
    for (int i = 0; i < 4; ++i) {             // chunk 0 of Wb -> buf 0
        int idx4 = t + i * 512;
        int e = idx4 >> 3, fq = idx4 & 7;
        float4 v = Wb4[(size_t)e * 64 + fq];
        half4x h = { (_Float16)v.x, (_Float16)v.y, (_Float16)v.z, (_Float16)v.w };
        *reinterpret_cast<half4x*>(&sWb0[e * WSTR + (fq << 2)]) = h;
    }
    sWcol[t]       = Wd[t * 32 + k];   // t<256: Wd1 col, t>=256: Wd2 col
    sWcol[512 + t] = Wg[t * 32 + k];
    __syncthreads();

    // ---- small dots: a1d/a2d/a1g/a2g (waves 0..3, lane = row index) ----
    if (w < 4) {
        const _Float16* row = (w & 1) ? &sA2[ln * LSTR] : &sA1[ln * LSTR];
        const float* wc = &sWcol[w * 256];
        float s = 0.f;
#pragma unroll 4
        for (int e = 0; e < 256; e += 4) {
            half4x h = *reinterpret_cast<const half4x*>(&row[e]);
            s += (float)h[0] * wc[e]     + (float)h[1] * wc[e + 1]
               + (float)h[2] * wc[e + 2] + (float)h[3] * wc[e + 3];
        }
        sDots[w * 64 + ln] = s;
    }

    // ---- GEMM1: R[e,n] = sum_f Wb[k,e,f]*a2[n,f]; 8 chunks, double-buffered ----
    floatx4 acc[2][4] = {};   // wave w owns e-rows [w*32, w*32+32), all 64 n
    for (int c = 0; c < 8; ++c) {
        const int cur = c & 1;
        // prefetch chunk c+1 into registers (hidden behind MFMAs below)
        float4 pv[4];
        if (c < 7) {
#pragma unroll
            for (int i = 0; i < 4; ++i) {
                int idx4 = t + i * 512;
                int e = idx4 >> 3, fq = idx4 & 7;
                pv[i] = Wb4[(size_t)e * 64 + (c + 1) * 8 + fq];
            }
        }
        half8 bf[4];
#pragma unroll
        for (int j = 0; j < 4; ++j)
            bf[j] = *reinterpret_cast<const half8*>(&sA2[(j * 16 + l16) * LSTR + c * 32 + q * 8]);
#pragma unroll
        for (int i2 = 0; i2 < 2; ++i2) {
            half8 af = *reinterpret_cast<const half8*>(&sWbBuf[cur][((w * 2 + i2) * 16 + l16) * WSTR + q * 8]);
#pragma unroll
            for (int j = 0; j < 4; ++j)
                acc[i2][j] = __builtin_amdgcn_mfma_f32_16x16x32_f16(af, bf[j], acc[i2][j], 0, 0, 0);
        }
        if (c < 7) {
#pragma unroll
            for (int i = 0; i < 4; ++i) {
                int idx4 = t + i * 512;
                int e = idx4 >> 3, fq = idx4 & 7;
                half4x h = { (_Float16)pv[i].x, (_Float16)pv[i].y,
                             (_Float16)pv[i].z, (_Float16)pv[i].w };
                *reinterpret_cast<half4x*>(&sWbBuf[cur ^ 1][e * WSTR + (fq << 2)]) = h;
            }
        }
        __syncthreads();   // next buf ready; cur-buf reads done before reuse
    }
    // after the final barrier sWb is dead -> sRT may reuse the aliased region

    // ---- write R^T to LDS (f16): C/D layout col=l16, row=q*4+r -> 4 consec e ----
#pragma unroll
    for (int i2 = 0; i2 < 2; ++i2)
#pragma unroll
        for (int j = 0; j < 4; ++j) {
            int e0 = w * 32 + i2 * 16 + q * 4;
            int n  = j * 16 + l16;
            floatx4 a = acc[i2][j];
            half4x h = { (_Float16)a[0], (_Float16)a[1], (_Float16)a[2], (_Float16)a[3] };
            *reinterpret_cast<half4x*>(&sRT[n * LSTR + e0]) = h;
        }
    __syncthreads();

    // ---- GEMM2: btp[m,n] = sum_e a1[m,e] * R[e,n]; wave -> (mt, 2 n-tiles) ----
    floatx4 acc2[2] = {};
    const int mt = w >> 1, np = w & 1;
#pragma unroll
    for (int es = 0; es < 8; ++es) {
        half8 a = *reinterpret_cast<const half8*>(&sA1[(mt * 16 + l16) * LSTR + es * 32 + q * 8]);
#pragma unroll
        for (int tt = 0; tt < 2; ++tt) {
            int nt = np * 2 + tt;
            half8 bb = *reinterpret_cast<const half8*>(&sRT[(nt * 16 + l16) * LSTR + es * 32 + q * 8]);
            acc2[tt] = __builtin_amdgcn_mfma_f32_16x16x32_f16(a, bb, acc2[tt], 0, 0, 0);
        }
    }

    // ---- epilogue: gate, tanh, scale by u[k]; write per-k contribution ----
    const float bgk = bg[k], bk = bvec[k], uk = u[k];
    float* cptr = contrib + ((size_t)(bi * 32 + k)) * 4096;
#pragma unroll
    for (int tt = 0; tt < 2; ++tt) {
        int n = (np * 2 + tt) * 16 + l16;
#pragma unroll
        for (int r = 0; r < 4; ++r) {
            int m = mt * 16 + q * 4 + r;
            float btp = acc2[tt][r];
            float zd  = sDots[m] + sDots[64 + n];
            float sln = 1.f - 2.f / (1.f + __expf(2.f * zd));      // tanh, overflow-safe
            float zg  = sDots[128 + m] + sDots[192 + n] + bgk;
            float g   = 1.f / (1.f + __expf(-zg));                 // sigmoid, overflow-safe
            float val = uk * (g * btp + (1.f - g) * sln + bk);
            cptr[m * 64 + n] = val;
        }
    }
}

__global__ __launch_bounds__(256) void grn_reduce_335007449190(
    const float* __restrict__ contrib, float* __restrict__ out)
{
    int i  = blockIdx.x * 256 + threadIdx.x;   // 32768 outputs
    int b  = i >> 12;
    int mn = i & 4095;
    const float* p = contrib + (size_t)b * 131072 + mn;
    float s = 0.f;
#pragma unroll
    for (int kk = 0; kk < 32; ++kk) s += p[kk * 4096];
    out[i] = s;
}

extern "C" void kernel_launch(void* const* d_in, const int* in_sizes, int n_in,
                              void* d_out, int out_size, void* d_ws, size_t ws_size,
                              hipStream_t stream) {
    const float* arg1 = (const float*)d_in[0];
    const float* arg2 = (const float*)d_in[1];
    const float* Wb   = (const float*)d_in[2];
    const float* Wd   = (const float*)d_in[3];
    const float* Wg   = (const float*)d_in[4];
    const float* bg   = (const float*)d_in[5];
    const float* bv   = (const float*)d_in[6];
    const float* u    = (const float*)d_in[7];
    float* out = (float*)d_out;

    float* contrib = (float*)d_ws;   // 4 MB needed
    grn_main_335007449190<<<256, 512, 0, stream>>>(arg1, arg2, Wb, Wd, Wg, bg, bv, u, contrib);
    grn_reduce_335007449190<<<128, 256, 0, stream>>>(contrib, out);
}

// Round 4
// 89.340 us; speedup vs baseline: 1.0278x; 1.0221x over previous
//
#include <hip/hip_runtime.h>

// GatedRelevanceNetwork: B=8, L1=L2=64, d=256, K=32
// out[b,m,n] = sum_k u[k] * ( g*btp + (1-g)*tanh(a1d[m,k]+a2d[n,k]) + b[k] )
// Block (b,k): R = Wb[k] @ a2^T (256x64), btp = a1 @ R (64x64), epilogue does
// k-reduction directly into d_out via native fp32 atomics (gfx950
// global_atomic_add_f32 through unsafeAtomicAdd) -- no ws, no reduce kernel.
// R3: fused single kernel. LDS 111 KiB (sWb[2] aliased with sRT).

#define LSTR 264   // padded stride (elems) for 256-wide f16 rows: bank step 4 -> free 2-way
#define WSTR 40    // padded stride for 32-wide Wb chunk rows

typedef _Float16 half8 __attribute__((ext_vector_type(8)));
typedef _Float16 half4x __attribute__((ext_vector_type(4)));
typedef float floatx4 __attribute__((ext_vector_type(4)));

__global__ __launch_bounds__(512, 2) void grn_main_335007449190(
    const float* __restrict__ arg1, const float* __restrict__ arg2,
    const float* __restrict__ Wb,   const float* __restrict__ Wd,
    const float* __restrict__ Wg,   const float* __restrict__ bg,
    const float* __restrict__ bvec, const float* __restrict__ u,
    float* __restrict__ outp)
{
    // Layout (bytes):
    //   [0,      33792)  sA1  : a1[m][e] f16, stride LSTR
    //   [33792,  67584)  sA2  : a2[n][f] f16, stride LSTR
    //   [67584, 108544)  union: sWb[2] (2 x 20480, GEMM1 phase)
    //                           sRT (33792, GEMM2 phase) -- never both live
    //   [108544,112640)  sWcol: Wd1|Wd2|Wg1|Wg2 columns k (f32 x 1024)
    //   [112640,113664)  sDots: a1d|a2d|a1g|a2g (f32 x 256)
    __shared__ __align__(16) char smem[113664];
    _Float16* sA1  = reinterpret_cast<_Float16*>(smem);
    _Float16* sA2  = reinterpret_cast<_Float16*>(smem + 33792);
    _Float16* sWb0 = reinterpret_cast<_Float16*>(smem + 67584);
    _Float16* sWb1 = reinterpret_cast<_Float16*>(smem + 67584 + 20480);
    _Float16* sRT  = reinterpret_cast<_Float16*>(smem + 67584);
    float*    sWcol= reinterpret_cast<float*>(smem + 108544);
    float*    sDots= reinterpret_cast<float*>(smem + 112640);
    _Float16* sWbBuf[2] = { sWb0, sWb1 };

    const int t   = threadIdx.x;
    const int bi  = blockIdx.x >> 5;
    const int k   = blockIdx.x & 31;
    const int w   = t >> 6;        // wave 0..7
    const int ln  = t & 63;
    const int q   = ln >> 4;       // quad 0..3
    const int l16 = ln & 15;

    const float4* Wb4 = reinterpret_cast<const float4*>(Wb) + (size_t)k * 16384;

    // ---- stage a1, a2 (f32 -> f16), Wb chunk 0, and Wd/Wg columns ----
    const float4* A1g = reinterpret_cast<const float4*>(arg1 + (size_t)bi * 64 * 256);
    const float4* A2g = reinterpret_cast<const float4*>(arg2 + (size_t)bi * 64 * 256);
#pragma unroll
    for (int i = 0; i < 8; ++i) {
        int idx4 = t + i * 512;               // 4096 float4s each
        int m = idx4 >> 6, f = (idx4 & 63) << 2;
        float4 v = A1g[idx4];
        half4x h1 = { (_Float16)v.x, (_Float16)v.y, (_Float16)v.z, (_Float16)v.w };
        *reinterpret_cast<half4x*>(&sA1[m * LSTR + f]) = h1;
        float4 u2 = A2g[idx4];
        half4x h2 = { (_Float16)u2.x, (_Float16)u2.y, (_Float16)u2.z, (_Float16)u2.w };
        *reinterpret_cast<half4x*>(&sA2[m * LSTR + f]) = h2;
    }
#pragma unroll
    for (int i = 0; i < 4; ++i) {             // chunk 0 of Wb -> buf 0
        int idx4 = t + i * 512;
        int e = idx4 >> 3, fq = idx4 & 7;
        float4 v = Wb4[(size_t)e * 64 + fq];
        half4x h = { (_Float16)v.x, (_Float16)v.y, (_Float16)v.z, (_Float16)v.w };
        *reinterpret_cast<half4x*>(&sWb0[e * WSTR + (fq << 2)]) = h;
    }
    sWcol[t]       = Wd[t * 32 + k];   // t<256: Wd1 col, t>=256: Wd2 col
    sWcol[512 + t] = Wg[t * 32 + k];
    __syncthreads();

    // ---- small dots: a1d/a2d/a1g/a2g (waves 0..3, lane = row index) ----
    if (w < 4) {
        const _Float16* row = (w & 1) ? &sA2[ln * LSTR] : &sA1[ln * LSTR];
        const float* wc = &sWcol[w * 256];
        float s = 0.f;
#pragma unroll 4
        for (int e = 0; e < 256; e += 4) {
            half4x h = *reinterpret_cast<const half4x*>(&row[e]);
            s += (float)h[0] * wc[e]     + (float)h[1] * wc[e + 1]
               + (float)h[2] * wc[e + 2] + (float)h[3] * wc[e + 3];
        }
        sDots[w * 64 + ln] = s;
    }

    // ---- GEMM1: R[e,n] = sum_f Wb[k,e,f]*a2[n,f]; 8 chunks, double-buffered ----
    floatx4 acc[2][4] = {};   // wave w owns e-rows [w*32, w*32+32), all 64 n
    for (int c = 0; c < 8; ++c) {
        const int cur = c & 1;
        // prefetch chunk c+1 into registers (hidden behind MFMAs below)
        float4 pv[4];
        if (c < 7) {
#pragma unroll
            for (int i = 0; i < 4; ++i) {
                int idx4 = t + i * 512;
                int e = idx4 >> 3, fq = idx4 & 7;
                pv[i] = Wb4[(size_t)e * 64 + (c + 1) * 8 + fq];
            }
        }
        half8 bf[4];
#pragma unroll
        for (int j = 0; j < 4; ++j)
            bf[j] = *reinterpret_cast<const half8*>(&sA2[(j * 16 + l16) * LSTR + c * 32 + q * 8]);
#pragma unroll
        for (int i2 = 0; i2 < 2; ++i2) {
            half8 af = *reinterpret_cast<const half8*>(&sWbBuf[cur][((w * 2 + i2) * 16 + l16) * WSTR + q * 8]);
#pragma unroll
            for (int j = 0; j < 4; ++j)
                acc[i2][j] = __builtin_amdgcn_mfma_f32_16x16x32_f16(af, bf[j], acc[i2][j], 0, 0, 0);
        }
        if (c < 7) {
#pragma unroll
            for (int i = 0; i < 4; ++i) {
                int idx4 = t + i * 512;
                int e = idx4 >> 3, fq = idx4 & 7;
                half4x h = { (_Float16)pv[i].x, (_Float16)pv[i].y,
                             (_Float16)pv[i].z, (_Float16)pv[i].w };
                *reinterpret_cast<half4x*>(&sWbBuf[cur ^ 1][e * WSTR + (fq << 2)]) = h;
            }
        }
        __syncthreads();   // next buf ready; cur-buf reads done before reuse
    }
    // after the final barrier sWb is dead -> sRT may reuse the aliased region

    // ---- write R^T to LDS (f16): C/D layout col=l16, row=q*4+r -> 4 consec e ----
#pragma unroll
    for (int i2 = 0; i2 < 2; ++i2)
#pragma unroll
        for (int j = 0; j < 4; ++j) {
            int e0 = w * 32 + i2 * 16 + q * 4;
            int n  = j * 16 + l16;
            floatx4 a = acc[i2][j];
            half4x h = { (_Float16)a[0], (_Float16)a[1], (_Float16)a[2], (_Float16)a[3] };
            *reinterpret_cast<half4x*>(&sRT[n * LSTR + e0]) = h;
        }
    __syncthreads();

    // ---- GEMM2: btp[m,n] = sum_e a1[m,e] * R[e,n]; wave -> (mt, 2 n-tiles) ----
    floatx4 acc2[2] = {};
    const int mt = w >> 1, np = w & 1;
#pragma unroll
    for (int es = 0; es < 8; ++es) {
        half8 a = *reinterpret_cast<const half8*>(&sA1[(mt * 16 + l16) * LSTR + es * 32 + q * 8]);
#pragma unroll
        for (int tt = 0; tt < 2; ++tt) {
            int nt = np * 2 + tt;
            half8 bb = *reinterpret_cast<const half8*>(&sRT[(nt * 16 + l16) * LSTR + es * 32 + q * 8]);
            acc2[tt] = __builtin_amdgcn_mfma_f32_16x16x32_f16(a, bb, acc2[tt], 0, 0, 0);
        }
    }

    // ---- epilogue: gate, tanh, scale by u[k]; k-reduce via HW fp32 atomics ----
    const float bgk = bg[k], bk = bvec[k], uk = u[k];
    float* optr = outp + (size_t)bi * 4096;
#pragma unroll
    for (int tt = 0; tt < 2; ++tt) {
        int n = (np * 2 + tt) * 16 + l16;
#pragma unroll
        for (int r = 0; r < 4; ++r) {
            int m = mt * 16 + q * 4 + r;
            float btp = acc2[tt][r];
            float zd  = sDots[m] + sDots[64 + n];
            float sln = 1.f - 2.f / (1.f + __expf(2.f * zd));      // tanh, overflow-safe
            float zg  = sDots[128 + m] + sDots[192 + n] + bgk;
            float g   = 1.f / (1.f + __expf(-zg));                 // sigmoid, overflow-safe
            float val = uk * (g * btp + (1.f - g) * sln + bk);
#if defined(__gfx950__) || defined(__AMDGCN__)
            unsafeAtomicAdd(&optr[m * 64 + n], val);   // native global_atomic_add_f32
#else
            atomicAdd(&optr[m * 64 + n], val);
#endif
        }
    }
}

extern "C" void kernel_launch(void* const* d_in, const int* in_sizes, int n_in,
                              void* d_out, int out_size, void* d_ws, size_t ws_size,
                              hipStream_t stream) {
    const float* arg1 = (const float*)d_in[0];
    const float* arg2 = (const float*)d_in[1];
    const float* Wb   = (const float*)d_in[2];
    const float* Wd   = (const float*)d_in[3];
    const float* Wg   = (const float*)d_in[4];
    const float* bg   = (const float*)d_in[5];
    const float* bv   = (const float*)d_in[6];
    const float* u    = (const float*)d_in[7];
    float* out = (float*)d_out;

    hipMemsetAsync(out, 0, (size_t)out_size * sizeof(float), stream);  // atomics need zeros
    grn_main_335007449190<<<256, 512, 0, stream>>>(arg1, arg2, Wb, Wd, Wg, bg, bv, u, out);
}